// Round 6
// baseline (5350.660 us; speedup 1.0000x reference)
//
#include <hip/hip_runtime.h>
#include <hip/hip_bf16.h>
#include <cstdint>
#include <cstring>

#define T_DIM 2048
#define B_DIM 64
#define H_DIM 256
#define NSLOT 1024
#define NWG_REC 64
#define MAXLOC 2048
#define HSTRIDE 264   // shorts; 132 dwords -> lane stride 4 banks, 2-way max

typedef __attribute__((ext_vector_type(8))) short bf16x8;
typedef __attribute__((ext_vector_type(4))) float f32x4;
typedef __attribute__((ext_vector_type(4))) short short4v;

// ---------------- ws layout (bytes) ----------------
static const size_t WS_GI      = 0;           // 201326592  gi bf16 T*B*768 (direct (t,b) layout)
static const size_t WS_RST     = 201326592;   // 131072     resets u8
static const size_t WS_FLAG    = 201457664;   // 8          dtype flag
static const size_t WS_LIST    = 201457672;   // 1048576    seg list u64
static const size_t WS_ASSIGN  = 202506248;   // 524288     per-seg ofs u32
static const size_t WS_WGSTEPS = 203030536;   // 256        u32[64]
static const size_t WS_TL      = 203030792;   // 8388608    timeline u32[NSLOT][MAXLOC]
// end ~211.4 MB < R4's proven 213.5 MB

// timeline record bits: t:0-10, b:11-16, ACTIVE:17, START:18, HINIT:19, FINAL:20
#define RB_ACT   (1u << 17)
#define RB_START (1u << 18)
#define RB_HINIT (1u << 19)
#define RB_FINAL (1u << 20)

static __device__ __forceinline__ short f2bs(float f) {
  __hip_bfloat16 b = __float2bfloat16(f);
  short s; memcpy(&s, &b, 2); return s;
}
static __device__ __forceinline__ float bs2f(unsigned short u) {
  uint32_t v = ((uint32_t)u) << 16; float f; memcpy(&f, &v, 4); return f;
}
static __device__ __forceinline__ float sigm(float x) {
  return 1.f / (1.f + __expf(-x));
}
static __device__ __forceinline__ float tanh_fast(float x) {
  return 1.f - 2.f / (__expf(2.f * x) + 1.f);
}

// ---------------- resets dtype detection (verified R1-R5) ----------------
__global__ __launch_bounds__(256) void detect_resets(const uint32_t* __restrict__ rbuf,
                                                     int* __restrict__ flag_out) {
  __shared__ int v_u8, v_f32;
  if (threadIdx.x == 0) { v_u8 = 0; v_f32 = 0; }
  __syncthreads();
  int cu = 0, cf = 0;
  for (int i = threadIdx.x; i < 32768; i += 256) {
    uint32_t w = rbuf[i];
    if (w == 0x3F800000u) cf++;
    else if (w > 1u && (w & 0xFEFEFEFEu) == 0u) cu++;
  }
  atomicAdd(&v_u8, cu);
  atomicAdd(&v_f32, cf);
  __syncthreads();
  if (threadIdx.x == 0) *flag_out = (v_f32 > 0) ? 2 : ((v_u8 > 0) ? 1 : 0);
}

__global__ __launch_bounds__(256) void expand_resets(const void* __restrict__ rbuf,
                                                     const int* __restrict__ flag,
                                                     uint8_t* __restrict__ out) {
  int i = blockIdx.x * 256 + threadIdx.x;
  if (i >= T_DIM * B_DIM) return;
  int f = *flag;
  uint8_t v;
  if (f == 1)      v = (((const uint8_t*)rbuf)[i] != 0);
  else if (f == 2) v = (((const float*)rbuf)[i] != 0.f);
  else             v = (((const int*)rbuf)[i] != 0);
  out[i] = v;
}

// ---------------- zero the timeline ----------------
__global__ __launch_bounds__(1024) void zero_tl(uint32_t* __restrict__ tl) {
  tl[(size_t)blockIdx.x * 1024 + threadIdx.x] = 0;
}

// ---------------- build segment schedule (parallel fill, verified R5) ----------------
__global__ __launch_bounds__(1024) void build_schedule(const uint8_t* __restrict__ rst,
                                                       uint64_t* __restrict__ listG,
                                                       uint32_t* __restrict__ assignG,
                                                       uint32_t* __restrict__ wgsteps,
                                                       uint32_t* __restrict__ tl) {
  __shared__ uint32_t slotload[NSLOT];
  __shared__ uint32_t cnt[64];
  __shared__ uint32_t offs[65];
  __shared__ uint32_t nseg_s;
  const int tid = threadIdx.x;

  for (int i = tid; i < NSLOT; i += 1024) slotload[i] = 0;
  __syncthreads();

  if (tid < 64) {
    int b = tid, k = 1;
    for (int t = 1; t < 2048; ++t) k += rst[t * 64 + b];
    cnt[b] = k;
  }
  __syncthreads();
  if (tid == 0) {
    uint32_t a = 0;
    for (int b2 = 0; b2 < 64; ++b2) { offs[b2] = a; a += cnt[b2]; }
    offs[64] = a; nseg_s = a;
  }
  __syncthreads();
  // emit segments.  u64: b:0-7 | hinit:8 | start:16-27 | len:32-47
  if (tid < 64) {
    int b = tid;
    uint32_t o = offs[b];
    int h0flag = rst[b] ? 0 : 1;
    int prev = 0;
    for (int t = 1; t < 2048; ++t) {
      if (rst[t * 64 + b]) {
        uint32_t hin = (prev == 0) ? (uint32_t)h0flag : 0u;
        listG[o++] = ((uint64_t)(uint32_t)(t - prev) << 32) |
                     ((uint32_t)prev << 16) | (hin << 8) | (uint32_t)b;
        prev = t;
      }
    }
    uint32_t hin = (prev == 0) ? (uint32_t)h0flag : 0u;
    listG[o++] = ((uint64_t)(uint32_t)(2048 - prev) << 32) |
                 ((uint32_t)prev << 16) | (hin << 8) | (uint32_t)b;
  }
  __syncthreads();
  const uint32_t NSEG = nseg_s;

  for (uint32_t s = tid; s < NSEG; s += 1024) {
    uint32_t len = (uint32_t)(listG[s] >> 32) & 0xFFFFu;
    assignG[s] = atomicAdd(&slotload[s & (NSLOT - 1)], len);
  }
  __syncthreads();

  if (tid < 64) {
    uint32_t mx = 0;
#pragma unroll
    for (int q = 0; q < 16; ++q) {
      uint32_t v = slotload[q * 64 + tid];
      mx = mx > v ? mx : v;
    }
    wgsteps[tid] = mx < MAXLOC ? mx : MAXLOC;
  }
  __syncthreads();

  // fill timeline: one wave per segment, lanes stride records
  const int wid = tid >> 6, ln = tid & 63;
  for (uint32_t s = wid; s < NSEG; s += 16) {
    uint64_t sg = listG[s];
    uint32_t slot = s & (NSLOT - 1);
    uint32_t ofs = assignG[s];
    uint32_t b = (uint32_t)sg & 63u;
    uint32_t hinit = ((uint32_t)sg >> 8) & 1u;
    uint32_t start = ((uint32_t)sg >> 16) & 0xFFFu;
    uint32_t len = (uint32_t)(sg >> 32) & 0xFFFFu;
    for (uint32_t i2 = ln; i2 < len; i2 += 64) {
      uint32_t rec = (start + i2) | (b << 11) | RB_ACT;
      if (i2 == 0) rec |= RB_START | (hinit << 19);
      if (i2 == len - 1 && start + len == 2048) rec |= RB_FINAL;
      if (ofs + i2 < MAXLOC) tl[(size_t)slot * MAXLOC + ofs + i2] = rec;
    }
  }
}

// ---------------- gi = x @ Wi + bi via MFMA (verified R2-R4, direct layout) ----------------
__global__ __launch_bounds__(1024) void gi_gemm_mfma(const float* __restrict__ x,
                                                     const float* __restrict__ Wi,
                                                     const float* __restrict__ bi,
                                                     unsigned short* __restrict__ gi16) {
  __shared__ short hfrag[32 * 136];
  const int tid = threadIdx.x;
  const int lane = tid & 63, wave = tid >> 6;
  const int lq = lane >> 4, l15 = lane & 15;

  bf16x8 wfrag[3][8];
  const int colb = wave * 48 + l15;
#pragma unroll
  for (int nt = 0; nt < 3; ++nt) {
#pragma unroll
    for (int ks = 0; ks < 8; ++ks) {
      bf16x8 f;
#pragma unroll
      for (int e = 0; e < 8; ++e)
        f[e] = f2bs(Wi[(size_t)(ks * 32 + lq * 8 + e) * 768 + colb + nt * 16]);
      wfrag[nt][ks] = f;
    }
  }
  const float b0 = bi[colb], b1 = bi[colb + 16], b2 = bi[colb + 32];

  const int r = wave;
  const int kc = (tid & 63) * 4;
  const size_t m0 = (size_t)blockIdx.x * 32 * 16;

  float4 xv = *(const float4*)&x[(m0 + r) * 256 + kc];
  for (int i = 0; i < 32; ++i) {
    short4v xb = { f2bs(xv.x), f2bs(xv.y), f2bs(xv.z), f2bs(xv.w) };
    *(short4v*)&hfrag[(kc >> 3) * 136 + r * 8 + (kc & 7)] = xb;
    __syncthreads();
    if (i + 1 < 32)
      xv = *(const float4*)&x[(m0 + (size_t)(i + 1) * 16 + r) * 256 + kc];
    f32x4 c0 = {0.f,0.f,0.f,0.f}, c1 = {0.f,0.f,0.f,0.f}, c2 = {0.f,0.f,0.f,0.f};
#pragma unroll
    for (int ks = 0; ks < 8; ++ks) {
      bf16x8 a = *(const bf16x8*)&hfrag[(ks * 4 + lq) * 136 + l15 * 8];
      c0 = __builtin_amdgcn_mfma_f32_16x16x32_bf16(a, wfrag[0][ks], c0, 0, 0, 0);
      c1 = __builtin_amdgcn_mfma_f32_16x16x32_bf16(a, wfrag[1][ks], c1, 0, 0, 0);
      c2 = __builtin_amdgcn_mfma_f32_16x16x32_bf16(a, wfrag[2][ks], c2, 0, 0, 0);
    }
    __syncthreads();
    const size_t rowb = m0 + (size_t)i * 16;
#pragma unroll
    for (int qq = 0; qq < 4; ++qq) {
      const size_t row = rowb + lq * 4 + qq;
      gi16[row * 768 + colb]      = (unsigned short)f2bs(c0[qq] + b0);
      gi16[row * 768 + colb + 16] = (unsigned short)f2bs(c1[qq] + b1);
      gi16[row * 768 + colb + 32] = (unsigned short)f2bs(c2[qq] + b2);
    }
  }
}

// ---------------- segment-parallel GRU recurrence (R4 geometry, fixed) ----------------
// 64 WGs x 16 waves. Slot of MFMA-col l15 = l15*64 + wg. Wave w owns h-cols
// [w*16, w*16+16); A-frags of ALL THREE gates resident in registers (96/thread,
// AGPR-backed as in R3). No weight LDS. One raw s_barrier/step draining LDS
// only — gi/tl prefetches stay in flight across it.
__global__ __launch_bounds__(1024) void gru_rec_seg(const unsigned short* __restrict__ gi16,
                                                    const float* __restrict__ h0,
                                                    const float* __restrict__ Whr,
                                                    const float* __restrict__ Whz,
                                                    const float* __restrict__ Whn,
                                                    const float* __restrict__ bhn,
                                                    const uint32_t* __restrict__ tl,
                                                    const uint32_t* __restrict__ wgsteps,
                                                    float* __restrict__ out) {
  __shared__ short hfrag[2][16 * HSTRIDE];   // [slot][hcol], 2x8.25KB
  const int tid = threadIdx.x;
  const int lane = tid & 63, w = tid >> 6;
  const int lq = lane >> 4, l15 = lane & 15;
  const int wg = blockIdx.x;

  // resident A-fragments: lane (lq,l15) holds W[k=ks*32+lq*8+e][w*16+l15]
  bf16x8 wfragR[8], wfragZ[8], wfragN[8];
  {
    const int wcol = w * 16 + l15;
#pragma unroll
    for (int ks = 0; ks < 8; ++ks) {
      bf16x8 fr, fz, fn;
#pragma unroll
      for (int e = 0; e < 8; ++e) {
        const size_t kk = (size_t)(ks * 32 + lq * 8 + e) * 256 + wcol;
        fr[e] = f2bs(Whr[kk]);
        fz[e] = f2bs(Whz[kk]);
        fn[e] = f2bs(Whn[kk]);
      }
      wfragR[ks] = fr; wfragZ[ks] = fz; wfragN[ks] = fn;
    }
  }

  const int colb = w * 16 + lq * 4;          // this thread's 4 output cols
  const float4 bnv = *(const float4*)&bhn[colb];
  const int nsteps = (int)wgsteps[wg];
  const uint32_t* tlb = tl + (size_t)(l15 * 64 + wg) * MAXLOC;

  uint32_t R0 = tlb[0], R1 = tlb[1];
  ushort4 G0a, G0b, G0c;
  {
    size_t gb = ((size_t)(R0 & 0x7FFu) * 64 + ((R0 >> 11) & 63u)) * 768 + colb;
    G0a = *(const ushort4*)&gi16[gb];
    G0b = *(const ushort4*)&gi16[gb + 256];
    G0c = *(const ushort4*)&gi16[gb + 512];
  }
  float hreg[4];
  {
    float4 hv = {0.f, 0.f, 0.f, 0.f};
    if ((R0 & RB_ACT) && (R0 & RB_START) && (R0 & RB_HINIT))
      hv = *(const float4*)&h0[(size_t)((R0 >> 11) & 63u) * 256 + colb];
    hreg[0] = hv.x; hreg[1] = hv.y; hreg[2] = hv.z; hreg[3] = hv.w;
    short4v hb = { f2bs(hv.x), f2bs(hv.y), f2bs(hv.z), f2bs(hv.w) };
    *(short4v*)&hfrag[0][l15 * HSTRIDE + colb] = hb;
  }
  __syncthreads();

  int cur = 0;
  for (int i = 0; i < nsteps; ++i) {
    // prefetch record i+2 and gi for step i+1 (stay in flight across barrier)
    uint32_t R2 = (i + 2 < MAXLOC) ? tlb[i + 2] : 0u;
    ushort4 G1a, G1b, G1c;
    {
      size_t gb = ((size_t)(R1 & 0x7FFu) * 64 + ((R1 >> 11) & 63u)) * 768 + colb;
      G1a = *(const ushort4*)&gi16[gb];
      G1b = *(const ushort4*)&gi16[gb + 256];
      G1c = *(const ushort4*)&gi16[gb + 512];
    }

    // C[gate][wcol][slot] = W^T x h^T ; B-op hv reused across 3 gates
    f32x4 c0 = {0.f,0.f,0.f,0.f}, c1 = {0.f,0.f,0.f,0.f}, c2 = {0.f,0.f,0.f,0.f};
    const short* hbase = &hfrag[cur][l15 * HSTRIDE + lq * 8];
#pragma unroll
    for (int ks = 0; ks < 8; ++ks) {
      bf16x8 hv = *(const bf16x8*)&hbase[ks * 32];
      c0 = __builtin_amdgcn_mfma_f32_16x16x32_bf16(wfragR[ks], hv, c0, 0, 0, 0);
      c1 = __builtin_amdgcn_mfma_f32_16x16x32_bf16(wfragZ[ks], hv, c1, 0, 0, 0);
      c2 = __builtin_amdgcn_mfma_f32_16x16x32_bf16(wfragN[ks], hv, c2, 0, 0, 0);
    }

    // pointwise for slot l15, cols colb..colb+3
    const unsigned short* g0 = (const unsigned short*)&G0a;
    const unsigned short* g1 = (const unsigned short*)&G0b;
    const unsigned short* g2 = (const unsigned short*)&G0c;
    float hn_[4];
#pragma unroll
    for (int qq = 0; qq < 4; ++qq) {
      float rr = sigm(bs2f(g0[qq]) + c0[qq]);
      float zz = sigm(bs2f(g1[qq]) + c1[qq]);
      float bn = (qq == 0) ? bnv.x : (qq == 1) ? bnv.y : (qq == 2) ? bnv.z : bnv.w;
      float nn = tanh_fast(bs2f(g2[qq]) + rr * (c2[qq] + bn));
      hn_[qq] = (1.f - zz) * nn + zz * hreg[qq];
    }
    if (R0 & RB_ACT) {
      uint32_t t = R0 & 0x7FFu, b = (R0 >> 11) & 63u;
      float4 ho = { hn_[0], hn_[1], hn_[2], hn_[3] };
      *(float4*)&out[16384 + ((size_t)t * 64 + b) * 256 + colb] = ho;
      if (R0 & RB_FINAL)
        *(float4*)&out[(size_t)b * 256 + colb] = ho;
    }

    // next h per R1 flags
    float4 hx = { hn_[0], hn_[1], hn_[2], hn_[3] };
    if (!(R1 & RB_ACT)) {
      hx.x = hx.y = hx.z = hx.w = 0.f;
    } else if (R1 & RB_START) {
      if (R1 & RB_HINIT)
        hx = *(const float4*)&h0[(size_t)((R1 >> 11) & 63u) * 256 + colb];
      else { hx.x = hx.y = hx.z = hx.w = 0.f; }
    }
    hreg[0] = hx.x; hreg[1] = hx.y; hreg[2] = hx.z; hreg[3] = hx.w;
    short4v hb = { f2bs(hx.x), f2bs(hx.y), f2bs(hx.z), f2bs(hx.w) };
    *(short4v*)&hfrag[cur ^ 1][l15 * HSTRIDE + colb] = hb;

    R0 = R1; R1 = R2;
    G0a = G1a; G0b = G1b; G0c = G1c;
    cur ^= 1;

    // raw barrier: drain LDS only; global prefetches remain in flight
    __builtin_amdgcn_sched_barrier(0);
    asm volatile("s_waitcnt lgkmcnt(0)" ::: "memory");
    __builtin_amdgcn_s_barrier();
    __builtin_amdgcn_sched_barrier(0);
  }
}

extern "C" void kernel_launch(void* const* d_in, const int* in_sizes, int n_in,
                              void* d_out, int out_size, void* d_ws, size_t ws_size,
                              hipStream_t stream) {
  const float* x   = (const float*)d_in[0];
  const void*  rin = d_in[1];
  const float* h0  = (const float*)d_in[2];
  const float* Wi  = (const float*)d_in[3];
  const float* bi  = (const float*)d_in[4];
  const float* Whr = (const float*)d_in[5];
  const float* Whz = (const float*)d_in[6];
  const float* Whn = (const float*)d_in[7];
  const float* bhn = (const float*)d_in[8];
  float* out = (float*)d_out;

  char* ws = (char*)d_ws;
  unsigned short* gi = (unsigned short*)(ws + WS_GI);
  uint8_t* rst       = (uint8_t*)(ws + WS_RST);
  int* flag          = (int*)(ws + WS_FLAG);
  uint64_t* listG    = (uint64_t*)(ws + WS_LIST);
  uint32_t* assignG  = (uint32_t*)(ws + WS_ASSIGN);
  uint32_t* wgsteps  = (uint32_t*)(ws + WS_WGSTEPS);
  uint32_t* tl       = (uint32_t*)(ws + WS_TL);

  hipLaunchKernelGGL(detect_resets, dim3(1), dim3(256), 0, stream,
                     (const uint32_t*)rin, flag);
  hipLaunchKernelGGL(expand_resets, dim3(512), dim3(256), 0, stream, rin, flag, rst);
  hipLaunchKernelGGL(zero_tl, dim3(MAXLOC), dim3(1024), 0, stream, tl);
  hipLaunchKernelGGL(build_schedule, dim3(1), dim3(1024), 0, stream,
                     rst, listG, assignG, wgsteps, tl);
  hipLaunchKernelGGL(gi_gemm_mfma, dim3(256), dim3(1024), 0, stream, x, Wi, bi, gi);
  hipLaunchKernelGGL(gru_rec_seg, dim3(NWG_REC), dim3(1024), 0, stream,
                     gi, h0, Whr, Whz, Whn, bhn, tl, wgsteps, out);
}

// Round 7
// 2690.248 us; speedup vs baseline: 1.9889x; 1.9889x over previous
//
#include <hip/hip_runtime.h>
#include <hip/hip_bf16.h>
#include <cstdint>
#include <cstring>

#define T_DIM 2048
#define B_DIM 64
#define H_DIM 256
#define NSLOT 2048
#define NWG_REC 128
#define MAXLOC 1280
#define HSTRIDE 264   // shorts; 528B rows, 16B-aligned, start-slot = (l15+lq+4ks)%8 -> ~2-way

typedef __attribute__((ext_vector_type(8))) short bf16x8;
typedef __attribute__((ext_vector_type(4))) float f32x4;
typedef __attribute__((ext_vector_type(4))) short short4v;

// ---------------- ws layout (bytes) ----------------
static const size_t WS_GI      = 0;           // 201326592  gi bf16 T*B*768 (direct (t,b) layout)
static const size_t WS_RST     = 201326592;   // 131072     resets u8
static const size_t WS_FLAG    = 201457664;   // 8          dtype flag
static const size_t WS_LIST    = 201457672;   // 1048576    seg list u64
static const size_t WS_ASSIGN  = 202506248;   // 524288     per-seg ofs u32
static const size_t WS_WGSTEPS = 203030536;   // 512        u32[128]
static const size_t WS_TL      = 203031048;   // 10485760   timeline u32[NSLOT][MAXLOC]
// end 213516808 (~213.5 MB, = R3/R4 proven footprint +256B)

// timeline record bits: t:0-10, b:11-16, ACTIVE:17, START:18, HINIT:19, FINAL:20
#define RB_ACT   (1u << 17)
#define RB_START (1u << 18)
#define RB_HINIT (1u << 19)
#define RB_FINAL (1u << 20)

static __device__ __forceinline__ short f2bs(float f) {
  __hip_bfloat16 b = __float2bfloat16(f);
  short s; memcpy(&s, &b, 2); return s;
}
static __device__ __forceinline__ float bs2f(unsigned short u) {
  uint32_t v = ((uint32_t)u) << 16; float f; memcpy(&f, &v, 4); return f;
}
static __device__ __forceinline__ float sigm(float x) {
  return 1.f / (1.f + __expf(-x));
}
static __device__ __forceinline__ float tanh_fast(float x) {
  return 1.f - 2.f / (__expf(2.f * x) + 1.f);
}

// ---------------- resets dtype detection (verified R1-R6) ----------------
__global__ __launch_bounds__(256) void detect_resets(const uint32_t* __restrict__ rbuf,
                                                     int* __restrict__ flag_out) {
  __shared__ int v_u8, v_f32;
  if (threadIdx.x == 0) { v_u8 = 0; v_f32 = 0; }
  __syncthreads();
  int cu = 0, cf = 0;
  for (int i = threadIdx.x; i < 32768; i += 256) {
    uint32_t w = rbuf[i];
    if (w == 0x3F800000u) cf++;
    else if (w > 1u && (w & 0xFEFEFEFEu) == 0u) cu++;
  }
  atomicAdd(&v_u8, cu);
  atomicAdd(&v_f32, cf);
  __syncthreads();
  if (threadIdx.x == 0) *flag_out = (v_f32 > 0) ? 2 : ((v_u8 > 0) ? 1 : 0);
}

__global__ __launch_bounds__(256) void expand_resets(const void* __restrict__ rbuf,
                                                     const int* __restrict__ flag,
                                                     uint8_t* __restrict__ out) {
  int i = blockIdx.x * 256 + threadIdx.x;
  if (i >= T_DIM * B_DIM) return;
  int f = *flag;
  uint8_t v;
  if (f == 1)      v = (((const uint8_t*)rbuf)[i] != 0);
  else if (f == 2) v = (((const float*)rbuf)[i] != 0.f);
  else             v = (((const int*)rbuf)[i] != 0);
  out[i] = v;
}

// ---------------- zero the timeline ----------------
__global__ __launch_bounds__(1024) void zero_tl(uint32_t* __restrict__ tl) {
  tl[(size_t)blockIdx.x * 1024 + threadIdx.x] = 0;
}

// ---------------- build segment schedule (parallel fill, verified R5/R6) ----------------
__global__ __launch_bounds__(1024) void build_schedule(const uint8_t* __restrict__ rst,
                                                       uint64_t* __restrict__ listG,
                                                       uint32_t* __restrict__ assignG,
                                                       uint32_t* __restrict__ wgsteps,
                                                       uint32_t* __restrict__ tl) {
  __shared__ uint32_t slotload[NSLOT];
  __shared__ uint32_t cnt[64];
  __shared__ uint32_t offs[65];
  __shared__ uint32_t nseg_s;
  const int tid = threadIdx.x;

  for (int i = tid; i < NSLOT; i += 1024) slotload[i] = 0;
  __syncthreads();

  if (tid < 64) {
    int b = tid, k = 1;
    for (int t = 1; t < 2048; ++t) k += rst[t * 64 + b];
    cnt[b] = k;
  }
  __syncthreads();
  if (tid == 0) {
    uint32_t a = 0;
    for (int b2 = 0; b2 < 64; ++b2) { offs[b2] = a; a += cnt[b2]; }
    offs[64] = a; nseg_s = a;
  }
  __syncthreads();
  // emit segments.  u64: b:0-7 | hinit:8 | start:16-27 | len:32-47
  if (tid < 64) {
    int b = tid;
    uint32_t o = offs[b];
    int h0flag = rst[b] ? 0 : 1;
    int prev = 0;
    for (int t = 1; t < 2048; ++t) {
      if (rst[t * 64 + b]) {
        uint32_t hin = (prev == 0) ? (uint32_t)h0flag : 0u;
        listG[o++] = ((uint64_t)(uint32_t)(t - prev) << 32) |
                     ((uint32_t)prev << 16) | (hin << 8) | (uint32_t)b;
        prev = t;
      }
    }
    uint32_t hin = (prev == 0) ? (uint32_t)h0flag : 0u;
    listG[o++] = ((uint64_t)(uint32_t)(2048 - prev) << 32) |
                 ((uint32_t)prev << 16) | (hin << 8) | (uint32_t)b;
  }
  __syncthreads();
  const uint32_t NSEG = nseg_s;

  for (uint32_t s = tid; s < NSEG; s += 1024) {
    uint32_t len = (uint32_t)(listG[s] >> 32) & 0xFFFFu;
    assignG[s] = atomicAdd(&slotload[s & (NSLOT - 1)], len);
  }
  __syncthreads();

  if (tid < NWG_REC) {
    uint32_t mx = 0;
#pragma unroll
    for (int q = 0; q < 16; ++q) {
      uint32_t v = slotload[q * NWG_REC + tid];
      mx = mx > v ? mx : v;
    }
    wgsteps[tid] = mx < MAXLOC ? mx : MAXLOC;
  }
  __syncthreads();

  // fill timeline: one wave per segment, lanes stride records
  const int wid = tid >> 6, ln = tid & 63;
  for (uint32_t s = wid; s < NSEG; s += 16) {
    uint64_t sg = listG[s];
    uint32_t slot = s & (NSLOT - 1);
    uint32_t ofs = assignG[s];
    uint32_t b = (uint32_t)sg & 63u;
    uint32_t hinit = ((uint32_t)sg >> 8) & 1u;
    uint32_t start = ((uint32_t)sg >> 16) & 0xFFFu;
    uint32_t len = (uint32_t)(sg >> 32) & 0xFFFFu;
    for (uint32_t i2 = ln; i2 < len; i2 += 64) {
      uint32_t rec = (start + i2) | (b << 11) | RB_ACT;
      if (i2 == 0) rec |= RB_START | (hinit << 19);
      if (i2 == len - 1 && start + len == 2048) rec |= RB_FINAL;
      if (ofs + i2 < MAXLOC) tl[(size_t)slot * MAXLOC + ofs + i2] = rec;
    }
  }
}

// ---------------- gi = x @ Wi + bi via MFMA (verified R2-R6) ----------------
__global__ __launch_bounds__(1024) void gi_gemm_mfma(const float* __restrict__ x,
                                                     const float* __restrict__ Wi,
                                                     const float* __restrict__ bi,
                                                     unsigned short* __restrict__ gi16) {
  __shared__ short hfrag[32 * 136];
  const int tid = threadIdx.x;
  const int lane = tid & 63, wave = tid >> 6;
  const int lq = lane >> 4, l15 = lane & 15;

  bf16x8 wfrag[3][8];
  const int colb = wave * 48 + l15;
#pragma unroll
  for (int nt = 0; nt < 3; ++nt) {
#pragma unroll
    for (int ks = 0; ks < 8; ++ks) {
      bf16x8 f;
#pragma unroll
      for (int e = 0; e < 8; ++e)
        f[e] = f2bs(Wi[(size_t)(ks * 32 + lq * 8 + e) * 768 + colb + nt * 16]);
      wfrag[nt][ks] = f;
    }
  }
  const float b0 = bi[colb], b1 = bi[colb + 16], b2 = bi[colb + 32];

  const int r = wave;
  const int kc = (tid & 63) * 4;
  const size_t m0 = (size_t)blockIdx.x * 32 * 16;

  float4 xv = *(const float4*)&x[(m0 + r) * 256 + kc];
  for (int i = 0; i < 32; ++i) {
    short4v xb = { f2bs(xv.x), f2bs(xv.y), f2bs(xv.z), f2bs(xv.w) };
    *(short4v*)&hfrag[(kc >> 3) * 136 + r * 8 + (kc & 7)] = xb;
    __syncthreads();
    if (i + 1 < 32)
      xv = *(const float4*)&x[(m0 + (size_t)(i + 1) * 16 + r) * 256 + kc];
    f32x4 c0 = {0.f,0.f,0.f,0.f}, c1 = {0.f,0.f,0.f,0.f}, c2 = {0.f,0.f,0.f,0.f};
#pragma unroll
    for (int ks = 0; ks < 8; ++ks) {
      bf16x8 a = *(const bf16x8*)&hfrag[(ks * 4 + lq) * 136 + l15 * 8];
      c0 = __builtin_amdgcn_mfma_f32_16x16x32_bf16(a, wfrag[0][ks], c0, 0, 0, 0);
      c1 = __builtin_amdgcn_mfma_f32_16x16x32_bf16(a, wfrag[1][ks], c1, 0, 0, 0);
      c2 = __builtin_amdgcn_mfma_f32_16x16x32_bf16(a, wfrag[2][ks], c2, 0, 0, 0);
    }
    __syncthreads();
    const size_t rowb = m0 + (size_t)i * 16;
#pragma unroll
    for (int qq = 0; qq < 4; ++qq) {
      const size_t row = rowb + lq * 4 + qq;
      gi16[row * 768 + colb]      = (unsigned short)f2bs(c0[qq] + b0);
      gi16[row * 768 + colb + 16] = (unsigned short)f2bs(c1[qq] + b1);
      gi16[row * 768 + colb + 32] = (unsigned short)f2bs(c2[qq] + b2);
    }
  }
}

// ---------------- segment-parallel GRU recurrence (R4-exact inner loop) ----------------
// 128 WGs x 16 waves, slot of MFMA-col l15 = l15*128 + wg. Wave w owns h-cols
// [w*16, w*16+16): Wr/Wz A-frags resident in VGPRs, Wn^T staged in LDS.
// __syncthreads per step (proven R4). Depth-1 gi prefetch.
__global__ __launch_bounds__(1024) void gru_rec_seg(const unsigned short* __restrict__ gi16,
                                                    const float* __restrict__ h0,
                                                    const float* __restrict__ Whr,
                                                    const float* __restrict__ Whz,
                                                    const float* __restrict__ Whn,
                                                    const float* __restrict__ bhn,
                                                    const uint32_t* __restrict__ tl,
                                                    const uint32_t* __restrict__ wgsteps,
                                                    float* __restrict__ out) {
  __shared__ short wn_lds[256 * HSTRIDE];     // Wn^T: [col][k], 135KB
  __shared__ short hfrag[2][16 * HSTRIDE];    // h^T: [slot][hcol], 2x8.4KB
  const int tid = threadIdx.x;
  const int lane = tid & 63, w = tid >> 6;
  const int lq = lane >> 4, l15 = lane & 15;
  const int wg = blockIdx.x;

  // resident Wr/Wz A-fragments: lane (lq,l15) holds W[k=ks*32+lq*8+e][w*16+l15]
  bf16x8 wfragR[8], wfragZ[8];
  {
    const int wcol = w * 16 + l15;
#pragma unroll
    for (int ks = 0; ks < 8; ++ks) {
      bf16x8 fr, fz;
#pragma unroll
      for (int e = 0; e < 8; ++e) {
        fr[e] = f2bs(Whr[(size_t)(ks * 32 + lq * 8 + e) * 256 + wcol]);
        fz[e] = f2bs(Whz[(size_t)(ks * 32 + lq * 8 + e) * 256 + wcol]);
      }
      wfragR[ks] = fr; wfragZ[ks] = fz;
    }
  }

  // stage Wn^T into LDS col-major: wn_lds[col*HSTRIDE + k]
  {
    const int col = tid & 255, kb = (tid >> 8) * 64;
    for (int kk = 0; kk < 64; kk += 4) {
      short4v v;
#pragma unroll
      for (int u = 0; u < 4; ++u)
        v[u] = f2bs(Whn[(size_t)(kb + kk + u) * 256 + col]);
      *(short4v*)&wn_lds[col * HSTRIDE + kb + kk] = v;
    }
  }

  const int col0 = w * 16 + lq * 4;           // this thread's 4 output cols
  const float4 bnv = *(const float4*)&bhn[col0];
  const int nsteps = (int)wgsteps[wg];
  const uint32_t* tlb = tl + (size_t)(l15 * NWG_REC + wg) * MAXLOC;

  // pipelines: records depth-2, gi depth-1
  uint32_t R0 = tlb[0], R1 = tlb[1];
  ushort4 G0a, G0b, G0c;
  {
    size_t gb = ((size_t)(R0 & 0x7FFu) * 64 + ((R0 >> 11) & 63u)) * 768 + col0;
    G0a = *(const ushort4*)&gi16[gb];
    G0b = *(const ushort4*)&gi16[gb + 256];
    G0c = *(const ushort4*)&gi16[gb + 512];
  }
  float hreg[4];
  {
    float4 hv = {0.f, 0.f, 0.f, 0.f};
    if ((R0 & RB_ACT) && (R0 & RB_START) && (R0 & RB_HINIT))
      hv = *(const float4*)&h0[(size_t)((R0 >> 11) & 63u) * 256 + col0];
    hreg[0] = hv.x; hreg[1] = hv.y; hreg[2] = hv.z; hreg[3] = hv.w;
    short4v hb = { f2bs(hv.x), f2bs(hv.y), f2bs(hv.z), f2bs(hv.w) };
    *(short4v*)&hfrag[0][l15 * HSTRIDE + col0] = hb;
  }
  __syncthreads();

  int cur = 0;
  for (int i = 0; i < nsteps; ++i) {
    // prefetch record i+2 and gi for step i+1
    uint32_t R2 = (i + 2 < MAXLOC) ? tlb[i + 2] : 0u;
    ushort4 G1a, G1b, G1c;
    {
      size_t gb = ((size_t)(R1 & 0x7FFu) * 64 + ((R1 >> 11) & 63u)) * 768 + col0;
      G1a = *(const ushort4*)&gi16[gb];
      G1b = *(const ushort4*)&gi16[gb + 256];
      G1c = *(const ushort4*)&gi16[gb + 512];
    }

    // C[gate][wcol][slot] = W^T x h^T
    f32x4 c0 = {0.f,0.f,0.f,0.f}, c1 = {0.f,0.f,0.f,0.f}, c2 = {0.f,0.f,0.f,0.f};
    const short* hbase = &hfrag[cur][l15 * HSTRIDE + lq * 8];
    const short* wnbase = &wn_lds[(w * 16 + l15) * HSTRIDE + lq * 8];
#pragma unroll
    for (int ks = 0; ks < 8; ++ks) {
      bf16x8 hv = *(const bf16x8*)&hbase[ks * 32];
      bf16x8 wv = *(const bf16x8*)&wnbase[ks * 32];
      c0 = __builtin_amdgcn_mfma_f32_16x16x32_bf16(wfragR[ks], hv, c0, 0, 0, 0);
      c1 = __builtin_amdgcn_mfma_f32_16x16x32_bf16(wfragZ[ks], hv, c1, 0, 0, 0);
      c2 = __builtin_amdgcn_mfma_f32_16x16x32_bf16(wv, hv, c2, 0, 0, 0);
    }

    // pointwise for slot l15, cols col0..col0+3
    const unsigned short* g0 = (const unsigned short*)&G0a;
    const unsigned short* g1 = (const unsigned short*)&G0b;
    const unsigned short* g2 = (const unsigned short*)&G0c;
    float hn_[4];
#pragma unroll
    for (int qq = 0; qq < 4; ++qq) {
      float rr = sigm(bs2f(g0[qq]) + c0[qq]);
      float zz = sigm(bs2f(g1[qq]) + c1[qq]);
      float bn = (qq == 0) ? bnv.x : (qq == 1) ? bnv.y : (qq == 2) ? bnv.z : bnv.w;
      float nn = tanh_fast(bs2f(g2[qq]) + rr * (c2[qq] + bn));
      hn_[qq] = (1.f - zz) * nn + zz * hreg[qq];
    }
    if (R0 & RB_ACT) {
      uint32_t t = R0 & 0x7FFu, b = (R0 >> 11) & 63u;
      float4 ho = { hn_[0], hn_[1], hn_[2], hn_[3] };
      *(float4*)&out[16384 + ((size_t)t * 64 + b) * 256 + col0] = ho;
      if (R0 & RB_FINAL)
        *(float4*)&out[(size_t)b * 256 + col0] = ho;
    }

    // next h: segment boundaries
    float4 hx = { hn_[0], hn_[1], hn_[2], hn_[3] };
    if (!(R1 & RB_ACT)) {
      hx.x = hx.y = hx.z = hx.w = 0.f;
    } else if (R1 & RB_START) {
      if (R1 & RB_HINIT)
        hx = *(const float4*)&h0[(size_t)((R1 >> 11) & 63u) * 256 + col0];
      else { hx.x = hx.y = hx.z = hx.w = 0.f; }
    }
    hreg[0] = hx.x; hreg[1] = hx.y; hreg[2] = hx.z; hreg[3] = hx.w;
    short4v hb = { f2bs(hx.x), f2bs(hx.y), f2bs(hx.z), f2bs(hx.w) };
    *(short4v*)&hfrag[cur ^ 1][l15 * HSTRIDE + col0] = hb;

    R0 = R1; R1 = R2;
    G0a = G1a; G0b = G1b; G0c = G1c;
    cur ^= 1;
    __syncthreads();
  }
}

extern "C" void kernel_launch(void* const* d_in, const int* in_sizes, int n_in,
                              void* d_out, int out_size, void* d_ws, size_t ws_size,
                              hipStream_t stream) {
  const float* x   = (const float*)d_in[0];
  const void*  rin = d_in[1];
  const float* h0  = (const float*)d_in[2];
  const float* Wi  = (const float*)d_in[3];
  const float* bi  = (const float*)d_in[4];
  const float* Whr = (const float*)d_in[5];
  const float* Whz = (const float*)d_in[6];
  const float* Whn = (const float*)d_in[7];
  const float* bhn = (const float*)d_in[8];
  float* out = (float*)d_out;

  char* ws = (char*)d_ws;
  unsigned short* gi = (unsigned short*)(ws + WS_GI);
  uint8_t* rst       = (uint8_t*)(ws + WS_RST);
  int* flag          = (int*)(ws + WS_FLAG);
  uint64_t* listG    = (uint64_t*)(ws + WS_LIST);
  uint32_t* assignG  = (uint32_t*)(ws + WS_ASSIGN);
  uint32_t* wgsteps  = (uint32_t*)(ws + WS_WGSTEPS);
  uint32_t* tl       = (uint32_t*)(ws + WS_TL);

  hipLaunchKernelGGL(detect_resets, dim3(1), dim3(256), 0, stream,
                     (const uint32_t*)rin, flag);
  hipLaunchKernelGGL(expand_resets, dim3(512), dim3(256), 0, stream, rin, flag, rst);
  hipLaunchKernelGGL(zero_tl, dim3((NSLOT * MAXLOC) / 1024), dim3(1024), 0, stream, tl);
  hipLaunchKernelGGL(build_schedule, dim3(1), dim3(1024), 0, stream,
                     rst, listG, assignG, wgsteps, tl);
  hipLaunchKernelGGL(gi_gemm_mfma, dim3(256), dim3(1024), 0, stream, x, Wi, bi, gi);
  hipLaunchKernelGGL(gru_rec_seg, dim3(NWG_REC), dim3(1024), 0, stream,
                     gi, h0, Whr, Whz, Whn, bhn, tl, wgsteps, out);
}